// Round 12
// baseline (301.511 us; speedup 1.0000x reference)
//
#include <hip/hip_runtime.h>
#include <math.h>

#define N_NODES 50000
#define N_PAD 50048                     // 64-row padded
#define E_EDGES 800000
#define E_PAD (E_EDGES + 8 * N_NODES)   // padded srclist capacity (rows padded to x8) = 1.2M
#define FDIM_IN 128
#define HID_1 32
#define HEADS_1 8
#define H1DIM 256
#define NUM_WALKS 512
#define WALK_LEN 64
#define WINDOW 5
#define NEG_S 10
#define TEMP 0.07f
#define INV_TEMP (1.0f / 0.07f)
#define NEG_SLOPE 0.2f
#define LOG2E 1.44269504f

#define SCAN_BLOCKS ((N_NODES + 255) / 256)   // 196 (scan_c2 grid)

// ---- two-pass CSR geometry (XCD-group-private regions) ----
#define NB 98                           // buckets (512 nodes each, dst>>9)
#define NGRP 8                          // XCD groups (blockIdx&7)
#define GCAP 1536                       // per-(group,bucket) region (uints); mean 1020 (+16 sigma)
#define LCAP 32                         // per-block per-bucket LDS slots; mean 10.4 (+6.7 sigma, w/ fallback)
#define BIN_BLOCKS 784                  // 784 * 1024 = 802816 >= 800000

typedef unsigned int uint;
typedef unsigned short ushort;
typedef long long i64_t;
typedef __attribute__((ext_vector_type(8))) short bf16x8;
typedef __attribute__((ext_vector_type(8))) ushort us8;
typedef __attribute__((ext_vector_type(4))) float f32x4;
typedef __attribute__((ext_vector_type(2))) float vf2;
typedef __attribute__((ext_vector_type(2))) i64_t i64x2;
typedef __attribute__((ext_vector_type(4))) uint u32x4;

__device__ __forceinline__ float leaky(float v) {
    return fmaxf(v, v * NEG_SLOPE);
}

__device__ __forceinline__ float bfl(uint u) { return __uint_as_float(u << 16); }
__device__ __forceinline__ float bfh(uint u) { return __uint_as_float(u & 0xffff0000u); }

__device__ __forceinline__ ushort f2bf(float x) {
    uint u = __float_as_uint(x);
    u = u + 0x7fffu + ((u >> 16) & 1u);   // round-to-nearest-even
    return (ushort)(u >> 16);
}

// pack 4 f32 -> 4 fp8(e4m3) in one uint (HW converter; self-consistent with decode)
__device__ __forceinline__ uint pk4fp8(float a, float b, float c, float d) {
    int u = __builtin_amdgcn_cvt_pk_fp8_f32(a, b, 0, false);
    u = __builtin_amdgcn_cvt_pk_fp8_f32(c, d, u, true);
    return (uint)u;
}

// 16-lane (row) sum reduction via DPP: xor1, xor2, half_mirror, mirror.
__device__ __forceinline__ float red16(float x) {
    int v = __float_as_int(x);
    x += __int_as_float(__builtin_amdgcn_update_dpp(0, v, 0xB1, 0xF, 0xF, true));   // quad_perm xor1
    v = __float_as_int(x);
    x += __int_as_float(__builtin_amdgcn_update_dpp(0, v, 0x4E, 0xF, 0xF, true));   // quad_perm xor2
    v = __float_as_int(x);
    x += __int_as_float(__builtin_amdgcn_update_dpp(0, v, 0x141, 0xF, 0xF, true));  // row_half_mirror
    v = __float_as_int(x);
    x += __int_as_float(__builtin_amdgcn_update_dpp(0, v, 0x140, 0xF, 0xF, true));  // row_mirror
    return x;
}

// ---------------- fused prep: bf16 convert + W transposes + sentinel init + EDGE BINNING ----------------
// bin role: 784 blocks, group g=blockIdx&7 (one XCD per group) appends packed (dst<<16|src)
// into GROUP-PRIVATE bucket regions. NO global degree atomics -- degrees are re-derived
// from the bucket data in scan_a via LDS counters.

#define PB_CVT  6250                     // 50000*128/4 / 256 (exact)
#define PO_WT1  (PB_CVT)
#define PO_WT2  (PO_WT1 + 128)
#define PO_MISC (PO_WT2 + 256)
#define PO_BIN  (PO_MISC + 1)
#define PREP_GRID (PO_BIN + BIN_BLOCKS)

__global__ __launch_bounds__(256) void prep_kernel(
        const float* __restrict__ x, const int* __restrict__ ei,
        const float* __restrict__ W1, const float* __restrict__ W2,
        uint* __restrict__ xb, ushort* __restrict__ wt1, ushort* __restrict__ wt2,
        uint* __restrict__ gbucket, int* __restrict__ gcur,
        float* __restrict__ als1, float* __restrict__ als2, uint* __restrict__ xw8) {
    const int blk = blockIdx.x, t = threadIdx.x;
    if (blk < PB_CVT) {
        int i = blk * 256 + t;
        float4 v = ((const float4*)x)[i];
        uint2 p;
        p.x = (uint)f2bf(v.x) | ((uint)f2bf(v.y) << 16);
        p.y = (uint)f2bf(v.z) | ((uint)f2bf(v.w) << 16);
        ((uint2*)xb)[i] = p;
    } else if (blk < PO_WT2) {
        int tid = (blk - PO_WT1) * 256 + t;
        int k = tid >> 8, n = tid & 255;
        wt1[n * 128 + k] = f2bf(W1[k * 256 + n]);
    } else if (blk < PO_MISC) {
        int tid = (blk - PO_WT2) * 256 + t;
        int k = tid >> 8, n = tid & 255;
        wt2[n * 256 + k] = f2bf(W2[k * 256 + n]);
    } else if (blk < PO_BIN) {
        if (t < HEADS_1) als1[N_NODES * HEADS_1 + t] = -1e30f;
        if (t == HEADS_1) als2[N_NODES] = -1e30f;
        if (t >= 64 && t < 128) xw8[N_NODES * 64 + (t - 64)] = 0u;   // zero sentinel fp8 row
    } else {
        // ---- bin role (append-only) ----
        __shared__ int scnt[NB];
        __shared__ int gposs[NB];
        __shared__ uint sbuf[NB * LCAP];     // 12.5 KB
        const int g = blk & 7;               // XCD group (round-robin dispatch)
        int* gc = gcur + g * NB;
        uint* gb = gbucket + (size_t)g * NB * GCAP;
        if (t < NB) scnt[t] = 0;
        __syncthreads();
        const int e0 = (blk - PO_BIN) * 1024;
#pragma unroll
        for (int k = 0; k < 4; k++) {
            int e = e0 + k * 256 + t;
            if (e < E_EDGES) {
                int dst = ei[E_EDGES + e];
                int src = ei[e];
                uint packed = ((uint)dst << 16) | (uint)src;
                int bk = dst >> 9;
                int pos = atomicAdd(&scnt[bk], 1);
                if (pos < LCAP) sbuf[bk * LCAP + pos] = packed;
                else {           // rare overflow: direct append (same cursor keeps allocation consistent)
                    int gp = atomicAdd(&gc[bk], 1);
                    gb[bk * GCAP + gp] = packed;
                }
            }
        }
        __syncthreads();
        if (t < NB) {
            int c = scnt[t]; if (c > LCAP) c = LCAP;
            gposs[t] = atomicAdd(&gc[t], c);
            scnt[t] = c;
        }
        __syncthreads();
        const int w2 = t >> 6, lane = t & 63;
        for (int b2 = w2; b2 < NB; b2 += 4) {
            int c = scnt[b2], gp = gposs[b2];
            for (int i = lane; i < c; i += 64)
                gb[b2 * GCAP + gp + i] = sbuf[b2 * LCAP + i];
        }
    }
}

// ---------------- CSR scan A: per-bucket degree count (from bucket data) + local prefix ----------------

__global__ __launch_bounds__(256) void scan_a(
        const uint* __restrict__ gbucket, const int* __restrict__ gcur,
        int* __restrict__ excl, int* __restrict__ bsum) {
    __shared__ int cnt[512];
    __shared__ int s[256];
    const int b = blockIdx.x, t = threadIdx.x;
    const int nlo = b << 9;
    cnt[t] = 0; cnt[t + 256] = 0;
    __syncthreads();
    for (int g = 0; g < NGRP; g++) {
        const uint* gb = gbucket + ((size_t)g * NB + b) * GCAP;
        const int c = gcur[g * NB + b];
        for (int i = t; i < c; i += 256)
            atomicAdd(&cnt[(gb[i] >> 16) - nlo], 1);
    }
    __syncthreads();
    const int v0 = (cnt[2 * t] + 7) & ~7;        // padded degrees (x8)
    const int v1 = (cnt[2 * t + 1] + 7) & ~7;    // nodes >= N_NODES have cnt 0 -> pad 0
    const int vs = v0 + v1;
    s[t] = vs;
    __syncthreads();
    for (int off = 1; off < 256; off <<= 1) {
        int tmp = (t >= off) ? s[t - off] : 0;
        __syncthreads();
        s[t] += tmp;
        __syncthreads();
    }
    const int ex = s[t] - vs;
    const int n0 = nlo + 2 * t;
    if (n0 < N_NODES) excl[n0] = ex;
    if (n0 + 1 < N_NODES) excl[n0 + 1] = ex + v0;
    if (t == 255) bsum[b] = s[255];
}

__global__ __launch_bounds__(128) void scan_b(int* __restrict__ bsum, int* __restrict__ row_start) {
    __shared__ int s[128];
    int t = threadIdx.x;
    int v = (t < NB) ? bsum[t] : 0;
    s[t] = v;
    __syncthreads();
    for (int off = 1; off < 128; off <<= 1) {
        int tmp = (t >= off) ? s[t - off] : 0;
        __syncthreads();
        s[t] += tmp;
        __syncthreads();
    }
    if (t < NB) bsum[t] = s[t] - v;   // exclusive
    if (t == 127) row_start[N_NODES] = s[127];   // grand total
}

__global__ void scan_c2(const int* __restrict__ excl, const int* __restrict__ bsum,
                        int* __restrict__ row_start) {
    int i = blockIdx.x * blockDim.x + threadIdx.x;
    if (i < N_NODES) row_start[i] = excl[i] + bsum[i >> 9];
}

// ---- MFMA GEMM, 64-row blocks, fused attention-logit epilogue (register-based) ----
// H==8 (layer 1): first NB blocks run the CSR scatter pass instead (LDS-window build
// of the padded srclist span, full-line u32x4 writeback); hides under MFMA work.
template<int K, int H>
__global__ __launch_bounds__(256) void mfma_gemm64(
        const ushort* __restrict__ A,    // [Mpad][K] bf16
        const ushort* __restrict__ Wt,   // [256][K] bf16 (transposed)
        uint* __restrict__ Y8,           // [M][256] fp8, 64 uints/row
        const float* __restrict__ a_src, // [256]
        const float* __restrict__ a_dst,
        float* __restrict__ als, float* __restrict__ ald,
        const uint* __restrict__ gbucket, const int* __restrict__ gcur,
        const int* __restrict__ row_start, ushort* __restrict__ srclist) {
    constexpr int KP = K + 8;
    constexpr int K8 = K / 8;
    constexpr int AS_BYTES = 64 * KP * 2;
    constexpr int SMEM_BYTES = (H == 8) ? 34816 : (AS_BYTES + 2560);
    __shared__ __align__(16) char smem[SMEM_BYTES];
    int m0;
    if (H == 8) {
        if (blockIdx.x < NB) {
            // ---- scatter role: bucket b -> nodes [b*512, b*512+512) ----
            ushort* win = (ushort*)smem;          // 32768 B window
            int* cur = (int*)(smem + 32768);      // 2048 B cursors
            const int b = blockIdx.x, t = threadIdx.x;
            const int nlo = b << 9;
            const int nhi = (nlo + 512 < N_NODES) ? (nlo + 512) : N_NODES;
            const int base = row_start[nlo];
            const int end = row_start[nhi];
            const int span = end - base;          // <= 16384 (mean ~9984)
            for (int i = t; i < nhi - nlo; i += 256) cur[i] = row_start[nlo + i] - base;
            for (int i = t; i < span / 2; i += 256) ((uint*)win)[i] = 0xC350C350u;   // sentinel 50000
            __syncthreads();
            for (int g = 0; g < NGRP; g++) {
                const uint* gb = gbucket + ((size_t)g * NB + b) * GCAP;
                const int cnt = gcur[g * NB + b];
                for (int i = t; i < cnt; i += 256) {
                    uint packed = gb[i];
                    int dst = packed >> 16;
                    int slot = atomicAdd(&cur[dst - nlo], 1);
                    win[slot] = (ushort)(packed & 0xffffu);
                }
            }
            __syncthreads();
            u32x4* d4 = (u32x4*)(srclist + base);     // base % 8 == 0 (padded rows)
            const u32x4* s4 = (const u32x4*)win;
            for (int i = t; i < span / 8; i += 256) d4[i] = s4[i];
            return;
        }
        m0 = (blockIdx.x - NB) * 64;
    } else {
        m0 = blockIdx.x * 64;
    }
    ushort* As = (ushort*)smem;
    float (*sals)[5] = (float(*)[5])(smem + AS_BYTES);
    float (*sald)[5] = (float(*)[5])(smem + AS_BYTES + 1280);
    const int t = threadIdx.x;
    const uint4* Ag = (const uint4*)(A + (size_t)m0 * K);
    uint4* As4 = (uint4*)As;
    for (int i = t; i < 64 * K8; i += 256) {
        int r = i / K8, c8 = i % K8;
        As4[r * (K8 + 1) + c8] = Ag[i];
    }
    __syncthreads();
    const int wv = __builtin_amdgcn_readfirstlane(t >> 6);
    const int lane = t & 63;
    const int n0 = wv * 64;
    const int mrow = lane & 15, q = lane >> 4;
    f32x4 acc[4][4];
#pragma unroll
    for (int mt = 0; mt < 4; mt++)
#pragma unroll
        for (int i = 0; i < 4; i++) acc[mt][i] = (f32x4){0.f, 0.f, 0.f, 0.f};
#pragma unroll
    for (int k0 = 0; k0 < K; k0 += 32) {
        bf16x8 a[4], b[4];
#pragma unroll
        for (int mt = 0; mt < 4; mt++)
            a[mt] = *(const bf16x8*)(As + (mt * 16 + mrow) * KP + k0 + q * 8);
#pragma unroll
        for (int i = 0; i < 4; i++)
            b[i] = *(const bf16x8*)(Wt + (uint)(n0 + i * 16 + mrow) * K + k0 + q * 8);
#pragma unroll
        for (int mt = 0; mt < 4; mt++)
#pragma unroll
            for (int i = 0; i < 4; i++)
                acc[mt][i] = __builtin_amdgcn_mfma_f32_16x16x32_bf16(a[mt], b[i], acc[mt][i], 0, 0, 0);
    }
    // ---- fused attention-logit epilogue (registers + 16-lane butterflies) ----
    {
        float as[4], ad[4];
#pragma unroll
        for (int i = 0; i < 4; i++) {
            as[i] = a_src[n0 + i * 16 + mrow];
            ad[i] = a_dst[n0 + i * 16 + mrow];
        }
#pragma unroll
        for (int mt = 0; mt < 4; mt++) {
#pragma unroll
            for (int r = 0; r < 4; r++) {
                const int row = m0 + mt * 16 + q * 4 + r;
                if (H == 8) {
                    float ps0 = acc[mt][0][r] * as[0] + acc[mt][1][r] * as[1];
                    float ps1 = acc[mt][2][r] * as[2] + acc[mt][3][r] * as[3];
                    float pd0 = acc[mt][0][r] * ad[0] + acc[mt][1][r] * ad[1];
                    float pd1 = acc[mt][2][r] * ad[2] + acc[mt][3][r] * ad[3];
#pragma unroll
                    for (int o = 1; o < 16; o <<= 1) {
                        ps0 += __shfl_xor(ps0, o, 64); ps1 += __shfl_xor(ps1, o, 64);
                        pd0 += __shfl_xor(pd0, o, 64); pd1 += __shfl_xor(pd1, o, 64);
                    }
                    if (mrow == 0 && row < N_NODES) {
                        als[row * 8 + 2 * wv] = ps0 * LOG2E;
                        als[row * 8 + 2 * wv + 1] = ps1 * LOG2E;
                        ald[row * 8 + 2 * wv] = pd0 * LOG2E;
                        ald[row * 8 + 2 * wv + 1] = pd1 * LOG2E;
                    }
                } else {
                    float ps = acc[mt][0][r] * as[0] + acc[mt][1][r] * as[1]
                             + acc[mt][2][r] * as[2] + acc[mt][3][r] * as[3];
                    float pd = acc[mt][0][r] * ad[0] + acc[mt][1][r] * ad[1]
                             + acc[mt][2][r] * ad[2] + acc[mt][3][r] * ad[3];
#pragma unroll
                    for (int o = 1; o < 16; o <<= 1) {
                        ps += __shfl_xor(ps, o, 64); pd += __shfl_xor(pd, o, 64);
                    }
                    if (mrow == 0) {
                        sals[mt * 16 + q * 4 + r][wv] = ps;
                        sald[mt * 16 + q * 4 + r][wv] = pd;
                    }
                }
            }
        }
    }
    __syncthreads();                     // A-tile dead; sals complete
    if (H == 1 && t < 64) {
        const int row = m0 + t;
        if (row < N_NODES) {
            als[row] = (sals[t][0] + sals[t][1] + sals[t][2] + sals[t][3]) * LOG2E;
            ald[row] = (sald[t][0] + sald[t][1] + sald[t][2] + sald[t][3]) * LOG2E;
        }
    }
    float* S = (float*)smem + wv * 16 * 68;   // 16 rows x 68 floats, wave-private (in As region)
    const int prow = lane >> 2, pj = lane & 3;   // pack: lane -> (row-in-tile, uint4 j)
#pragma unroll
    for (int mt = 0; mt < 4; mt++) {
#pragma unroll
        for (int i = 0; i < 4; i++)
#pragma unroll
            for (int r = 0; r < 4; r++)
                S[(q * 4 + r) * 68 + i * 16 + mrow] = acc[mt][i][r];
        // wave-internal LDS ordering: no barrier needed
        const float* cp = S + prow * 68 + pj * 16;
        uint4 o;
        o.x = pk4fp8(cp[0],  cp[1],  cp[2],  cp[3]);
        o.y = pk4fp8(cp[4],  cp[5],  cp[6],  cp[7]);
        o.z = pk4fp8(cp[8],  cp[9],  cp[10], cp[11]);
        o.w = pk4fp8(cp[12], cp[13], cp[14], cp[15]);
        const int row = m0 + mt * 16 + prow;
        if (row < N_NODES)
            ((uint4*)(Y8 + (size_t)row * 64))[wv * 4 + pj] = o;
    }
}

// layer-1 gather: 2 edges per wave-instruction (lanes 0-31 = even edge, 32-63 = odd edge;
// each lane owns 8 dims via uint2 row loads). Halves row-load/addr/exp instruction streams.
// Final merge: one shfl_xor(32) over den + 8 accumulator floats; half 0 stores.
__global__ __launch_bounds__(256) void gat_gather1(
        const int* __restrict__ row_start, const ushort* __restrict__ srclist,
        const float* __restrict__ als, const float* __restrict__ ald,
        const uint* __restrict__ xw8,                    // fp8 rows, 64 uints/row
        const float* __restrict__ bias,
        ushort* __restrict__ emb1b) {                    // [N][256] bf16
    const int wid = __builtin_amdgcn_readfirstlane(blockIdx.x * 4 + (threadIdx.x >> 6));
    const uint lane = threadIdx.x & 63;
    const uint sl = lane & 31, half = lane >> 5;
    const uint h = sl >> 2;                              // head = dims(sl*8)/32
    const float ald_n = ald[wid * HEADS_1 + h];
    const int beg = row_start[wid], end = row_start[wid + 1];

    vf2 a[4];
    float den;
    {
        uint2 u = ((const uint2*)xw8)[((uint)wid << 5) + sl];
        float ex0 = (half == 0) ? __builtin_amdgcn_exp2f(leaky(als[wid * HEADS_1 + h] + ald_n)) : 0.f;
        vf2 e = {ex0, ex0};
        a[0] = e * __builtin_amdgcn_cvt_pk_f32_fp8((int)u.x, false);
        a[1] = e * __builtin_amdgcn_cvt_pk_f32_fp8((int)u.x, true);
        a[2] = e * __builtin_amdgcn_cvt_pk_f32_fp8((int)u.y, false);
        a[3] = e * __builtin_amdgcn_cvt_pk_f32_fp8((int)u.y, true);
        den = ex0;
    }
    for (int i = beg; i < end; i += 8) {
        us8 sv = *(const us8*)(srclist + i);   // wave-uniform 8 indices
#pragma unroll
        for (int p = 0; p < 4; p++) {
            uint r = (uint)sv[2 * p + half];
            uint2 rv = ((const uint2*)xw8)[(r << 5) + sl];
            float ex = __builtin_amdgcn_exp2f(leaky(als[r * HEADS_1 + h] + ald_n));   // sentinel -> 0
            den += ex;
            vf2 e = {ex, ex};
            a[0] += e * __builtin_amdgcn_cvt_pk_f32_fp8((int)rv.x, false);
            a[1] += e * __builtin_amdgcn_cvt_pk_f32_fp8((int)rv.x, true);
            a[2] += e * __builtin_amdgcn_cvt_pk_f32_fp8((int)rv.y, false);
            a[3] += e * __builtin_amdgcn_cvt_pk_f32_fp8((int)rv.y, true);
        }
    }
    // merge even/odd halves
    den += __shfl_xor(den, 32, 64);
#pragma unroll
    for (int k = 0; k < 4; k++) {
        a[k][0] += __shfl_xor(a[k][0], 32, 64);
        a[k][1] += __shfl_xor(a[k][1], 32, 64);
    }
    float inv = 1.f / den;
    float4 bv0 = ((const float4*)bias)[sl * 2];
    float4 bv1 = ((const float4*)bias)[sl * 2 + 1];
    float v0 = a[0][0] * inv + bv0.x, v1 = a[0][1] * inv + bv0.y;
    float v2 = a[1][0] * inv + bv0.z, v3 = a[1][1] * inv + bv0.w;
    float v4 = a[2][0] * inv + bv1.x, v5 = a[2][1] * inv + bv1.y;
    float v6 = a[3][0] * inv + bv1.z, v7 = a[3][1] * inv + bv1.w;
    v0 = v0 > 0.f ? v0 : __expf(v0) - 1.f;  v1 = v1 > 0.f ? v1 : __expf(v1) - 1.f;
    v2 = v2 > 0.f ? v2 : __expf(v2) - 1.f;  v3 = v3 > 0.f ? v3 : __expf(v3) - 1.f;
    v4 = v4 > 0.f ? v4 : __expf(v4) - 1.f;  v5 = v5 > 0.f ? v5 : __expf(v5) - 1.f;
    v6 = v6 > 0.f ? v6 : __expf(v6) - 1.f;  v7 = v7 > 0.f ? v7 : __expf(v7) - 1.f;
    if (half == 0) {
        uint4 o;
        o.x = (uint)f2bf(v0) | ((uint)f2bf(v1) << 16);
        o.y = (uint)f2bf(v2) | ((uint)f2bf(v3) << 16);
        o.z = (uint)f2bf(v4) | ((uint)f2bf(v5) << 16);
        o.w = (uint)f2bf(v6) | ((uint)f2bf(v7) << 16);
        ((uint4*)emb1b)[((uint)wid << 5) + sl] = o;
    }
}

// layer-2 gather (2-edges-per-instr scheme) fused with normalize + fp8 pack (PERMUTED layout).
__global__ __launch_bounds__(256) void gat_gather2(
        const int* __restrict__ row_start, const ushort* __restrict__ srclist,
        const float* __restrict__ als, const float* __restrict__ ald,
        const uint* __restrict__ xw8,                    // fp8 rows, 64 uints/row
        const float* __restrict__ bias,
        const ushort* __restrict__ emb1b,                // [N][256] bf16
        uint* __restrict__ embn8) {                      // [N][512] fp8 PERMUTED, 128 uints/row
    const int wid = __builtin_amdgcn_readfirstlane(blockIdx.x * 4 + (threadIdx.x >> 6));
    const uint lane = threadIdx.x & 63;
    const uint sl = lane & 31, half = lane >> 5;
    const float ald_n = ald[wid];
    const int beg = row_start[wid], end = row_start[wid + 1];

    vf2 a[4];
    float den;
    {
        uint2 u = ((const uint2*)xw8)[((uint)wid << 5) + sl];
        float ex0 = (half == 0) ? __builtin_amdgcn_exp2f(leaky(als[wid] + ald_n)) : 0.f;
        vf2 e = {ex0, ex0};
        a[0] = e * __builtin_amdgcn_cvt_pk_f32_fp8((int)u.x, false);
        a[1] = e * __builtin_amdgcn_cvt_pk_f32_fp8((int)u.x, true);
        a[2] = e * __builtin_amdgcn_cvt_pk_f32_fp8((int)u.y, false);
        a[3] = e * __builtin_amdgcn_cvt_pk_f32_fp8((int)u.y, true);
        den = ex0;
    }
    for (int i = beg; i < end; i += 8) {
        us8 sv = *(const us8*)(srclist + i);
#pragma unroll
        for (int p = 0; p < 4; p++) {
            uint r = (uint)sv[2 * p + half];
            uint2 rv = ((const uint2*)xw8)[(r << 5) + sl];
            float ex = __builtin_amdgcn_exp2f(leaky(als[r] + ald_n));   // sentinel -> 0
            den += ex;
            vf2 e = {ex, ex};
            a[0] += e * __builtin_amdgcn_cvt_pk_f32_fp8((int)rv.x, false);
            a[1] += e * __builtin_amdgcn_cvt_pk_f32_fp8((int)rv.x, true);
            a[2] += e * __builtin_amdgcn_cvt_pk_f32_fp8((int)rv.y, false);
            a[3] += e * __builtin_amdgcn_cvt_pk_f32_fp8((int)rv.y, true);
        }
    }
    den += __shfl_xor(den, 32, 64);
#pragma unroll
    for (int k = 0; k < 4; k++) {
        a[k][0] += __shfl_xor(a[k][0], 32, 64);
        a[k][1] += __shfl_xor(a[k][1], 32, 64);
    }
    float inv = 1.f / den;
    float4 bv0 = ((const float4*)bias)[sl * 2];
    float4 bv1 = ((const float4*)bias)[sl * 2 + 1];
    float e2[8];
    e2[0] = a[0][0] * inv + bv0.x; e2[1] = a[0][1] * inv + bv0.y;
    e2[2] = a[1][0] * inv + bv0.z; e2[3] = a[1][1] * inv + bv0.w;
    e2[4] = a[2][0] * inv + bv1.x; e2[5] = a[2][1] * inv + bv1.y;
    e2[6] = a[3][0] * inv + bv1.z; e2[7] = a[3][1] * inv + bv1.w;
    uint4 u1 = ((const uint4*)emb1b)[((uint)wid << 5) + sl];
    float e1[8];
    e1[0] = bfl(u1.x); e1[1] = bfh(u1.x); e1[2] = bfl(u1.y); e1[3] = bfh(u1.y);
    e1[4] = bfl(u1.z); e1[5] = bfh(u1.z); e1[6] = bfl(u1.w); e1[7] = bfh(u1.w);

    float ssum = 0.f;
#pragma unroll
    for (int k = 0; k < 8; k++) ssum += e1[k] * e1[k] + e2[k] * e2[k];
#pragma unroll
    for (int o = 16; o > 0; o >>= 1) ssum += __shfl_xor(ssum, o, 64);   // 32-lane group = full row
    float innv = 1.f / fmaxf(sqrtf(ssum), 1e-8f);

    if (half == 0) {
        uint2 p1, p2;
        p1.x = pk4fp8(e1[0] * innv, e1[1] * innv, e1[2] * innv, e1[3] * innv);
        p1.y = pk4fp8(e1[4] * innv, e1[5] * innv, e1[6] * innv, e1[7] * innv);
        p2.x = pk4fp8(e2[0] * innv, e2[1] * innv, e2[2] * innv, e2[3] * innv);
        p2.y = pk4fp8(e2[4] * innv, e2[5] * innv, e2[6] * innv, e2[7] * innv);
        // permuted pair store: uints (2sl, 2sl+1) map to consecutive slots n1(2sl), n1(2sl)+1
        const uint n1p = ((sl >> 3) << 4) | ((sl & 3) << 2) | (((sl >> 2) & 1) << 1);
        *(uint2*)(embn8 + ((uint)wid << 7) + n1p) = p1;        // emb1 part -> chunks j=0..3
        *(uint2*)(embn8 + ((uint)wid << 7) + 64 + n1p) = p2;   // emb2 part -> chunks j=4..7
    }
}

// ---------------- MFMA contrastive loss (fp8, permuted rows) ----------------

#define ROWU 140                        // 560 B row stride: 16B-aligned, b128 conflict-free

__global__ __launch_bounds__(1024, 8) void loss_mfma_kernel(
        const uint* __restrict__ embn8,    // [N][512] fp8 permuted, 128 uints/row
        const int* __restrict__ walks, const int* __restrict__ negs,
        float* __restrict__ out) {
    __shared__ __align__(16) uint srows8[WALK_LEN * ROWU];   // 35.8 KB
    __shared__ int wids[WALK_LEN];
    __shared__ float possum[WALK_LEN];
    __shared__ float negsum[WALK_LEN];
    const int b = blockIdx.x;                // walk
    const int t = threadIdx.x;
    const int w = __builtin_amdgcn_readfirstlane(t >> 6);   // 0..15
    const int lane = t & 63;
    const int mrow = lane & 15, q = lane >> 4;
    const char* embc = (const char*)embn8;   // byte rows, stride 512

    if (t < 64) wids[t] = walks[b * WALK_LEN + t];
    else if (t < 128) possum[t - 64] = 0.f;
    else if (t < 192) negsum[t - 128] = 0.f;

    // prefetch job0 (= w, always a neg tile) B rows into registers BEFORE the barriers:
    // latency rides under the staging drain.
    uint4 Bv[8];
    int pnode = negs[b * (WALK_LEN * NEG_S) + (w * 16 + mrow)];
    {
        const char* bp = embc + (((uint)pnode) << 9) + (uint)(q * 16);
#pragma unroll
        for (int j = 0; j < 8; j++) Bv[j] = *(const uint4*)(bp + j * 64);
    }
    __syncthreads();                         // wids ready

    // stage 64 walk rows (4 per wave, 2 rows per uint4 wave-instr)
    {
        const int rA = w * 4 + (lane >> 5);
        const int rB = rA + 2;
        const uint off = lane & 31;
        ((uint4*)(srows8 + rA * ROWU))[off] = ((const uint4*)embn8)[((uint)wids[rA] << 5) + off];
        ((uint4*)(srows8 + rB * ROWU))[off] = ((const uint4*)embn8)[((uint)wids[rB] << 5) + off];
    }
    __syncthreads();

#pragma unroll
    for (int ji = 0; ji < 3; ji++) {
        const int job = w + ji * 16;
        f32x4 acc0 = {0.f, 0.f, 0.f, 0.f};
        f32x4 acc1 = {0.f, 0.f, 0.f, 0.f};
        if (ji < 2 || w < 8) {
            // ---- neg tile: cands c = 16*job .. +15 (col = mrow), anchors = group job/10 ----
            const int albase = (job / 10) * 16;
            const int curnode = pnode;
            const int owner = (job * 16 + mrow) / 10;    // absolute anchor owning cand
            const char* ap = (const char*)(srows8 + (albase + mrow) * ROWU) + q * 16;
            __builtin_amdgcn_s_setprio(1);
#pragma unroll
            for (int j = 0; j < 4; j++) {
                i64x2 a = *(const i64x2*)(ap + j * 64);
                const i64x2 bb = *(const i64x2*)&Bv[j];
                acc0 = __builtin_amdgcn_mfma_f32_16x16x32_fp8_fp8(a[0], bb[0], acc0, 0, 0, 0);
                acc0 = __builtin_amdgcn_mfma_f32_16x16x32_fp8_fp8(a[1], bb[1], acc0, 0, 0, 0);
            }
#pragma unroll
            for (int j = 4; j < 8; j++) {
                i64x2 a = *(const i64x2*)(ap + j * 64);
                const i64x2 bb = *(const i64x2*)&Bv[j];
                acc1 = __builtin_amdgcn_mfma_f32_16x16x32_fp8_fp8(a[0], bb[0], acc1, 0, 0, 0);
                acc1 = __builtin_amdgcn_mfma_f32_16x16x32_fp8_fp8(a[1], bb[1], acc1, 0, 0, 0);
            }
            __builtin_amdgcn_s_setprio(0);
            // prefetch next job's B (Bv consumed above); latency hides under epilogue
            if (ji == 0 || (ji == 1 && w < 8)) {
                const int njob = job + 16;
                pnode = negs[b * (WALK_LEN * NEG_S) + (njob * 16 + mrow)];
                const char* bp = embc + (((uint)pnode) << 9) + (uint)(q * 16);
#pragma unroll
                for (int j = 0; j < 8; j++) Bv[j] = *(const uint4*)(bp + j * 64);
            }
#pragma unroll
            for (int reg = 0; reg < 4; reg++) {
                const int l_a = albase + q * 4 + reg;   // absolute anchor of this acc slot
                float e = 0.f;
                if (owner == l_a) {
                    bool msk = false;
#pragma unroll
                    for (int dj = -WINDOW; dj <= WINDOW; dj++) {
                        if (dj == 0) continue;
                        int p = l_a + dj;
                        if (p >= 0 && p < WALK_LEN && wids[p] == curnode) msk = true;
                    }
                    if (!msk) e = __expf((acc0[reg] + acc1[reg]) * INV_TEMP);
                }
                e = red16(e);
                if (mrow == 0 && e != 0.f) atomicAdd(&negsum[l_a], e);
            }
        } else {
            // ---- pos tile: group g = (w-8)>>1, row half = (w-8)&1 ----
            const int pj = w - 8;
            const int g = pj >> 1, half = pj & 1;
            const int albase = g * 16;
            const int base = (albase - WINDOW) > 0 ? (albase - WINDOW) : 0;
            const int hi = (albase + 15 + WINDOW) < (WALK_LEN - 1) ? (albase + 15 + WINDOW) : (WALK_LEN - 1);
            const int cnt = hi - base + 1;           // 21..26
            const int r = half * 16 + mrow;
            const int row = base + r;                // absolute walk pos of this B row
            const int rc = row < hi ? row : hi;      // clamp (masked by `use`)
            const char* ap = (const char*)(srows8 + (albase + mrow) * ROWU) + q * 16;
            const char* bp = (const char*)(srows8 + rc * ROWU) + q * 16;
            __builtin_amdgcn_s_setprio(1);
#pragma unroll
            for (int j = 0; j < 4; j++) {
                i64x2 a = *(const i64x2*)(ap + j * 64);
                i64x2 bb = *(const i64x2*)(bp + j * 64);
                acc0 = __builtin_amdgcn_mfma_f32_16x16x32_fp8_fp8(a[0], bb[0], acc0, 0, 0, 0);
                acc0 = __builtin_amdgcn_mfma_f32_16x16x32_fp8_fp8(a[1], bb[1], acc0, 0, 0, 0);
            }
#pragma unroll
            for (int j = 4; j < 8; j++) {
                i64x2 a = *(const i64x2*)(ap + j * 64);
                i64x2 bb = *(const i64x2*)(bp + j * 64);
                acc1 = __builtin_amdgcn_mfma_f32_16x16x32_fp8_fp8(a[0], bb[0], acc1, 0, 0, 0);
                acc1 = __builtin_amdgcn_mfma_f32_16x16x32_fp8_fp8(a[1], bb[1], acc1, 0, 0, 0);
            }
            __builtin_amdgcn_s_setprio(0);
#pragma unroll
            for (int reg = 0; reg < 4; reg++) {
                const int l_a = albase + q * 4 + reg;
                const int d = row - l_a;
                bool use = (r < cnt) && (d != 0) && (d >= -WINDOW) && (d <= WINDOW);
                float e = use ? __expf((acc0[reg] + acc1[reg]) * INV_TEMP) : 0.f;
                e = red16(e);
                if (mrow == 0 && e != 0.f) atomicAdd(&possum[l_a], e);
            }
        }
    }
    __syncthreads();
    if (t < 64) {
        float term = logf(1.f + negsum[t] / possum[t]);   // possum > 0 always
#pragma unroll
        for (int o = 32; o > 0; o >>= 1) term += __shfl_xor(term, o, 64);
        if (t == 0) atomicAdd(out, term);
    }
}

extern "C" void kernel_launch(void* const* d_in, const int* in_sizes, int n_in,
                              void* d_out, int out_size, void* d_ws, size_t ws_size,
                              hipStream_t stream) {
    const float* x      = (const float*)d_in[0];
    const int*   ei     = (const int*)d_in[1];
    const int*   walks  = (const int*)d_in[2];
    const int*   negs   = (const int*)d_in[3];
    const float* W1     = (const float*)d_in[4];
    const float* a_src1 = (const float*)d_in[5];
    const float* a_dst1 = (const float*)d_in[6];
    const float* b1     = (const float*)d_in[7];
    const float* W2     = (const float*)d_in[8];
    const float* a_src2 = (const float*)d_in[9];
    const float* a_dst2 = (const float*)d_in[10];
    const float* b2     = (const float*)d_in[11];
    float* out = (float*)d_out;

    float* ws = (float*)d_ws;
    size_t off = 0;
    // every region aligned to 1024 B (256 floats) so row starts stay cache-line aligned
#define ALIGN_OFF off = (off + 255) & ~(size_t)255
    float* r_xw8   = ws + off; off += (size_t)(N_NODES + 1) * 64;  ALIGN_OFF;  // [N+1][256] fp8 (sentinel row)
    float* r_emb1b = ws + off; off += (size_t)N_PAD * 128;         ALIGN_OFF;  // [Npad][256] bf16
    float* r_embn8 = ws + off; off += (size_t)N_NODES * 128;       ALIGN_OFF;  // [N][512] fp8 permuted
    float* r_xb    = ws + off; off += (size_t)N_PAD * 64;          ALIGN_OFF;  // [Npad][128] bf16
    float* r_wt1   = ws + off; off += 256 * 64;                    ALIGN_OFF;  // [256][128] bf16
    float* r_wt2   = ws + off; off += 256 * 128;                   ALIGN_OFF;  // [256][256] bf16
    float* als1  = ws + off; off += (N_NODES + 1) * HEADS_1;       ALIGN_OFF;  // sentinel row
    float* ald1  = ws + off; off += N_NODES * HEADS_1;             ALIGN_OFF;
    float* als2  = ws + off; off += N_NODES + 1;                   ALIGN_OFF;  // sentinel
    float* ald2  = ws + off; off += N_NODES;                       ALIGN_OFF;
    int* excl      = (int*)(ws + off); off += N_NODES;             ALIGN_OFF;
    int* bsum      = (int*)(ws + off); off += 256;                 ALIGN_OFF;
    int* row_start = (int*)(ws + off); off += N_NODES + 1;         ALIGN_OFF;
    uint* gbucket  = (uint*)(ws + off); off += (size_t)NGRP * NB * GCAP; ALIGN_OFF;  // 4.8 MB group-private regions
    int* gcur      = (int*)(ws + off); off += 1024;                ALIGN_OFF;
    ushort* srclist = (ushort*)(ws + off); off += E_PAD / 2;       ALIGN_OFF;  // 2B entries
    uint*   xw8   = (uint*)r_xw8;
    ushort* emb1b = (ushort*)r_emb1b;
    uint*   embn8 = (uint*)r_embn8;
    ushort* xb    = (ushort*)r_xb;
    ushort* wt1   = (ushort*)r_wt1;
    ushort* wt2   = (ushort*)r_wt2;

    hipMemsetAsync(out, 0, sizeof(float) * out_size, stream);
    hipMemsetAsync(gcur, 0, sizeof(int) * NGRP * NB, stream);

    // ---- fused prep (bf16 convert + W transposes + sentinel init + append-only binning) ----
    prep_kernel<<<PREP_GRID, 256, 0, stream>>>(
        x, ei, W1, W2, (uint*)xb, wt1, wt2, gbucket, gcur, als1, als2, xw8);

    // ---- CSR scans: degree-from-buckets (LDS counters) + per-bucket prefix + global prefix ----
    scan_a<<<NB, 256, 0, stream>>>(gbucket, gcur, excl, bsum);
    scan_b<<<1, 128, 0, stream>>>(bsum, row_start);
    scan_c2<<<SCAN_BLOCKS, 256, 0, stream>>>(excl, bsum, row_start);

    // ---- layer 1 gemm FUSED with LDS-window scatter (98 scatter + 782 gemm blocks) ----
    mfma_gemm64<128, HEADS_1><<<NB + N_PAD / 64, 256, 0, stream>>>(
        xb, wt1, xw8, a_src1, a_dst1, als1, ald1, gbucket, gcur, row_start, srclist);
    gat_gather1<<<N_NODES / 4, 256, 0, stream>>>(
        row_start, srclist, als1, ald1, xw8, b1, emb1b);

    // ---- layer 2 (heads=1, hid=256), fused als/ald + normalize + fp8 pack (permuted) ----
    mfma_gemm64<256, 1><<<N_PAD / 64, 256, 0, stream>>>(
        emb1b, wt2, xw8, a_src2, a_dst2, als2, ald2, gbucket, gcur, row_start, srclist);
    gat_gather2<<<N_NODES / 4, 256, 0, stream>>>(
        row_start, srclist, als2, ald2, xw8, b2, emb1b, embn8);

    // ---- contrastive loss (fp8 MFMA, 1 block/walk, reg-prefetch pipeline) ----
    loss_mfma_kernel<<<NUM_WALKS, 1024, 0, stream>>>(embn8, walks, negs, out);
}

// Round 13
// 291.453 us; speedup vs baseline: 1.0345x; 1.0345x over previous
//
#include <hip/hip_runtime.h>
#include <math.h>

#define N_NODES 50000
#define N_PAD 50048                     // 64-row padded
#define E_EDGES 800000
#define E_PAD (E_EDGES + 8 * N_NODES)   // padded srclist capacity (rows padded to x8) = 1.2M
#define FDIM_IN 128
#define HID_1 32
#define HEADS_1 8
#define H1DIM 256
#define NUM_WALKS 512
#define WALK_LEN 64
#define WINDOW 5
#define NEG_S 10
#define TEMP 0.07f
#define INV_TEMP (1.0f / 0.07f)
#define NEG_SLOPE 0.2f
#define LOG2E 1.44269504f

#define SCAN_BLOCKS ((N_NODES + 255) / 256)   // 196 (scan_c2 grid)

// ---- two-pass CSR geometry (XCD-group-private regions) ----
#define NB 98                           // buckets (512 nodes each, dst>>9)
#define NGRP 8                          // XCD groups (blockIdx&7)
#define GCAP 1536                       // per-(group,bucket) region (uints); mean 1020 (+16 sigma)
#define LCAP 32                         // per-block per-bucket LDS slots; mean 10.4 (+6.7 sigma, w/ fallback)
#define BIN_BLOCKS 784                  // 784 * 1024 = 802816 >= 800000

typedef unsigned int uint;
typedef unsigned short ushort;
typedef long long i64_t;
typedef __attribute__((ext_vector_type(8))) short bf16x8;
typedef __attribute__((ext_vector_type(8))) ushort us8;
typedef __attribute__((ext_vector_type(4))) float f32x4;
typedef __attribute__((ext_vector_type(2))) float vf2;
typedef __attribute__((ext_vector_type(2))) i64_t i64x2;
typedef __attribute__((ext_vector_type(4))) uint u32x4;

__device__ __forceinline__ float leaky(float v) {
    return fmaxf(v, v * NEG_SLOPE);
}

__device__ __forceinline__ float bfl(uint u) { return __uint_as_float(u << 16); }
__device__ __forceinline__ float bfh(uint u) { return __uint_as_float(u & 0xffff0000u); }

__device__ __forceinline__ ushort f2bf(float x) {
    uint u = __float_as_uint(x);
    u = u + 0x7fffu + ((u >> 16) & 1u);   // round-to-nearest-even
    return (ushort)(u >> 16);
}

// pack 4 f32 -> 4 fp8(e4m3) in one uint (HW converter; self-consistent with decode)
__device__ __forceinline__ uint pk4fp8(float a, float b, float c, float d) {
    int u = __builtin_amdgcn_cvt_pk_fp8_f32(a, b, 0, false);
    u = __builtin_amdgcn_cvt_pk_fp8_f32(c, d, u, true);
    return (uint)u;
}

// 16-lane (row) sum reduction via DPP: xor1, xor2, half_mirror, mirror.
__device__ __forceinline__ float red16(float x) {
    int v = __float_as_int(x);
    x += __int_as_float(__builtin_amdgcn_update_dpp(0, v, 0xB1, 0xF, 0xF, true));   // quad_perm xor1
    v = __float_as_int(x);
    x += __int_as_float(__builtin_amdgcn_update_dpp(0, v, 0x4E, 0xF, 0xF, true));   // quad_perm xor2
    v = __float_as_int(x);
    x += __int_as_float(__builtin_amdgcn_update_dpp(0, v, 0x141, 0xF, 0xF, true));  // row_half_mirror
    v = __float_as_int(x);
    x += __int_as_float(__builtin_amdgcn_update_dpp(0, v, 0x140, 0xF, 0xF, true));  // row_mirror
    return x;
}

// ---------------- fused prep: bf16 convert + W transposes + sentinel init + EDGE BINNING ----------------

#define PB_CVT  6250                     // 50000*128/4 / 256 (exact)
#define PO_WT1  (PB_CVT)
#define PO_WT2  (PO_WT1 + 128)
#define PO_MISC (PO_WT2 + 256)
#define PO_BIN  (PO_MISC + 1)
#define PREP_GRID (PO_BIN + BIN_BLOCKS)

__global__ __launch_bounds__(256) void prep_kernel(
        const float* __restrict__ x, const int* __restrict__ ei,
        const float* __restrict__ W1, const float* __restrict__ W2,
        uint* __restrict__ xb, ushort* __restrict__ wt1, ushort* __restrict__ wt2,
        uint* __restrict__ gbucket, int* __restrict__ gcur,
        float* __restrict__ als1, float* __restrict__ als2, uint* __restrict__ xw8) {
    const int blk = blockIdx.x, t = threadIdx.x;
    if (blk < PB_CVT) {
        int i = blk * 256 + t;
        float4 v = ((const float4*)x)[i];
        uint2 p;
        p.x = (uint)f2bf(v.x) | ((uint)f2bf(v.y) << 16);
        p.y = (uint)f2bf(v.z) | ((uint)f2bf(v.w) << 16);
        ((uint2*)xb)[i] = p;
    } else if (blk < PO_WT2) {
        int tid = (blk - PO_WT1) * 256 + t;
        int k = tid >> 8, n = tid & 255;
        wt1[n * 128 + k] = f2bf(W1[k * 256 + n]);
    } else if (blk < PO_MISC) {
        int tid = (blk - PO_WT2) * 256 + t;
        int k = tid >> 8, n = tid & 255;
        wt2[n * 256 + k] = f2bf(W2[k * 256 + n]);
    } else if (blk < PO_BIN) {
        if (t < HEADS_1) als1[N_NODES * HEADS_1 + t] = -1e30f;
        if (t == HEADS_1) als2[N_NODES] = -1e30f;
        if (t >= 64 && t < 128) xw8[N_NODES * 64 + (t - 64)] = 0u;   // zero sentinel fp8 row
    } else {
        // ---- bin role (append-only) ----
        __shared__ int scnt[NB];
        __shared__ int gposs[NB];
        __shared__ uint sbuf[NB * LCAP];     // 12.5 KB
        const int g = blk & 7;               // XCD group (round-robin dispatch)
        int* gc = gcur + g * NB;
        uint* gb = gbucket + (size_t)g * NB * GCAP;
        if (t < NB) scnt[t] = 0;
        __syncthreads();
        const int e0 = (blk - PO_BIN) * 1024;
#pragma unroll
        for (int k = 0; k < 4; k++) {
            int e = e0 + k * 256 + t;
            if (e < E_EDGES) {
                int dst = ei[E_EDGES + e];
                int src = ei[e];
                uint packed = ((uint)dst << 16) | (uint)src;
                int bk = dst >> 9;
                int pos = atomicAdd(&scnt[bk], 1);
                if (pos < LCAP) sbuf[bk * LCAP + pos] = packed;
                else {           // rare overflow: direct append (same cursor keeps allocation consistent)
                    int gp = atomicAdd(&gc[bk], 1);
                    gb[bk * GCAP + gp] = packed;
                }
            }
        }
        __syncthreads();
        if (t < NB) {
            int c = scnt[t]; if (c > LCAP) c = LCAP;
            gposs[t] = atomicAdd(&gc[t], c);
            scnt[t] = c;
        }
        __syncthreads();
        const int w2 = t >> 6, lane = t & 63;
        for (int b2 = w2; b2 < NB; b2 += 4) {
            int c = scnt[b2], gp = gposs[b2];
            for (int i = lane; i < c; i += 64)
                gb[b2 * GCAP + gp + i] = sbuf[b2 * LCAP + i];
        }
    }
}

// ---------------- CSR scan A: per-bucket degree count (from bucket data) + local prefix ----------------

__global__ __launch_bounds__(256) void scan_a(
        const uint* __restrict__ gbucket, const int* __restrict__ gcur,
        int* __restrict__ excl, int* __restrict__ bsum) {
    __shared__ int cnt[512];
    __shared__ int s[256];
    const int b = blockIdx.x, t = threadIdx.x;
    const int nlo = b << 9;
    cnt[t] = 0; cnt[t + 256] = 0;
    __syncthreads();
    for (int g = 0; g < NGRP; g++) {
        const uint* gb = gbucket + ((size_t)g * NB + b) * GCAP;
        const int c = gcur[g * NB + b];
        for (int i = t; i < c; i += 256)
            atomicAdd(&cnt[(gb[i] >> 16) - nlo], 1);
    }
    __syncthreads();
    const int v0 = (cnt[2 * t] + 7) & ~7;        // padded degrees (x8)
    const int v1 = (cnt[2 * t + 1] + 7) & ~7;    // nodes >= N_NODES have cnt 0 -> pad 0
    const int vs = v0 + v1;
    s[t] = vs;
    __syncthreads();
    for (int off = 1; off < 256; off <<= 1) {
        int tmp = (t >= off) ? s[t - off] : 0;
        __syncthreads();
        s[t] += tmp;
        __syncthreads();
    }
    const int ex = s[t] - vs;
    const int n0 = nlo + 2 * t;
    if (n0 < N_NODES) excl[n0] = ex;
    if (n0 + 1 < N_NODES) excl[n0 + 1] = ex + v0;
    if (t == 255) bsum[b] = s[255];
}

__global__ __launch_bounds__(128) void scan_b(int* __restrict__ bsum, int* __restrict__ row_start) {
    __shared__ int s[128];
    int t = threadIdx.x;
    int v = (t < NB) ? bsum[t] : 0;
    s[t] = v;
    __syncthreads();
    for (int off = 1; off < 128; off <<= 1) {
        int tmp = (t >= off) ? s[t - off] : 0;
        __syncthreads();
        s[t] += tmp;
        __syncthreads();
    }
    if (t < NB) bsum[t] = s[t] - v;   // exclusive
    if (t == 127) row_start[N_NODES] = s[127];   // grand total
}

__global__ void scan_c2(const int* __restrict__ excl, const int* __restrict__ bsum,
                        int* __restrict__ row_start) {
    int i = blockIdx.x * blockDim.x + threadIdx.x;
    if (i < N_NODES) row_start[i] = excl[i] + bsum[i >> 9];
}

// ---- MFMA GEMM, 64-row blocks, fused attention-logit epilogue (register-based) ----
// H==8 (layer 1): first NB blocks run the CSR scatter pass instead (LDS-window build
// of the padded srclist span, full-line u32x4 writeback); hides under MFMA work.
template<int K, int H>
__global__ __launch_bounds__(256) void mfma_gemm64(
        const ushort* __restrict__ A,    // [Mpad][K] bf16
        const ushort* __restrict__ Wt,   // [256][K] bf16 (transposed)
        uint* __restrict__ Y8,           // [M][256] fp8, 64 uints/row
        const float* __restrict__ a_src, // [256]
        const float* __restrict__ a_dst,
        float* __restrict__ als, float* __restrict__ ald,
        const uint* __restrict__ gbucket, const int* __restrict__ gcur,
        const int* __restrict__ row_start, ushort* __restrict__ srclist) {
    constexpr int KP = K + 8;
    constexpr int K8 = K / 8;
    constexpr int AS_BYTES = 64 * KP * 2;
    constexpr int SMEM_BYTES = (H == 8) ? 34816 : (AS_BYTES + 2560);
    __shared__ __align__(16) char smem[SMEM_BYTES];
    int m0;
    if (H == 8) {
        if (blockIdx.x < NB) {
            // ---- scatter role: bucket b -> nodes [b*512, b*512+512) ----
            ushort* win = (ushort*)smem;          // 32768 B window
            int* cur = (int*)(smem + 32768);      // 2048 B cursors
            const int b = blockIdx.x, t = threadIdx.x;
            const int nlo = b << 9;
            const int nhi = (nlo + 512 < N_NODES) ? (nlo + 512) : N_NODES;
            const int base = row_start[nlo];
            const int end = row_start[nhi];
            const int span = end - base;          // <= 16384 (mean ~9984)
            for (int i = t; i < nhi - nlo; i += 256) cur[i] = row_start[nlo + i] - base;
            for (int i = t; i < span / 2; i += 256) ((uint*)win)[i] = 0xC350C350u;   // sentinel 50000
            __syncthreads();
            for (int g = 0; g < NGRP; g++) {
                const uint* gb = gbucket + ((size_t)g * NB + b) * GCAP;
                const int cnt = gcur[g * NB + b];
                for (int i = t; i < cnt; i += 256) {
                    uint packed = gb[i];
                    int dst = packed >> 16;
                    int slot = atomicAdd(&cur[dst - nlo], 1);
                    win[slot] = (ushort)(packed & 0xffffu);
                }
            }
            __syncthreads();
            u32x4* d4 = (u32x4*)(srclist + base);     // base % 8 == 0 (padded rows)
            const u32x4* s4 = (const u32x4*)win;
            for (int i = t; i < span / 8; i += 256) d4[i] = s4[i];
            return;
        }
        m0 = (blockIdx.x - NB) * 64;
    } else {
        m0 = blockIdx.x * 64;
    }
    ushort* As = (ushort*)smem;
    float (*sals)[5] = (float(*)[5])(smem + AS_BYTES);
    float (*sald)[5] = (float(*)[5])(smem + AS_BYTES + 1280);
    const int t = threadIdx.x;
    const uint4* Ag = (const uint4*)(A + (size_t)m0 * K);
    uint4* As4 = (uint4*)As;
    for (int i = t; i < 64 * K8; i += 256) {
        int r = i / K8, c8 = i % K8;
        As4[r * (K8 + 1) + c8] = Ag[i];
    }
    __syncthreads();
    const int wv = __builtin_amdgcn_readfirstlane(t >> 6);
    const int lane = t & 63;
    const int n0 = wv * 64;
    const int mrow = lane & 15, q = lane >> 4;
    f32x4 acc[4][4];
#pragma unroll
    for (int mt = 0; mt < 4; mt++)
#pragma unroll
        for (int i = 0; i < 4; i++) acc[mt][i] = (f32x4){0.f, 0.f, 0.f, 0.f};
#pragma unroll
    for (int k0 = 0; k0 < K; k0 += 32) {
        bf16x8 a[4], b[4];
#pragma unroll
        for (int mt = 0; mt < 4; mt++)
            a[mt] = *(const bf16x8*)(As + (mt * 16 + mrow) * KP + k0 + q * 8);
#pragma unroll
        for (int i = 0; i < 4; i++)
            b[i] = *(const bf16x8*)(Wt + (uint)(n0 + i * 16 + mrow) * K + k0 + q * 8);
#pragma unroll
        for (int mt = 0; mt < 4; mt++)
#pragma unroll
            for (int i = 0; i < 4; i++)
                acc[mt][i] = __builtin_amdgcn_mfma_f32_16x16x32_bf16(a[mt], b[i], acc[mt][i], 0, 0, 0);
    }
    // ---- fused attention-logit epilogue (registers + 16-lane butterflies) ----
    {
        float as[4], ad[4];
#pragma unroll
        for (int i = 0; i < 4; i++) {
            as[i] = a_src[n0 + i * 16 + mrow];
            ad[i] = a_dst[n0 + i * 16 + mrow];
        }
#pragma unroll
        for (int mt = 0; mt < 4; mt++) {
#pragma unroll
            for (int r = 0; r < 4; r++) {
                const int row = m0 + mt * 16 + q * 4 + r;
                if (H == 8) {
                    float ps0 = acc[mt][0][r] * as[0] + acc[mt][1][r] * as[1];
                    float ps1 = acc[mt][2][r] * as[2] + acc[mt][3][r] * as[3];
                    float pd0 = acc[mt][0][r] * ad[0] + acc[mt][1][r] * ad[1];
                    float pd1 = acc[mt][2][r] * ad[2] + acc[mt][3][r] * ad[3];
#pragma unroll
                    for (int o = 1; o < 16; o <<= 1) {
                        ps0 += __shfl_xor(ps0, o, 64); ps1 += __shfl_xor(ps1, o, 64);
                        pd0 += __shfl_xor(pd0, o, 64); pd1 += __shfl_xor(pd1, o, 64);
                    }
                    if (mrow == 0 && row < N_NODES) {
                        als[row * 8 + 2 * wv] = ps0 * LOG2E;
                        als[row * 8 + 2 * wv + 1] = ps1 * LOG2E;
                        ald[row * 8 + 2 * wv] = pd0 * LOG2E;
                        ald[row * 8 + 2 * wv + 1] = pd1 * LOG2E;
                    }
                } else {
                    float ps = acc[mt][0][r] * as[0] + acc[mt][1][r] * as[1]
                             + acc[mt][2][r] * as[2] + acc[mt][3][r] * as[3];
                    float pd = acc[mt][0][r] * ad[0] + acc[mt][1][r] * ad[1]
                             + acc[mt][2][r] * ad[2] + acc[mt][3][r] * ad[3];
#pragma unroll
                    for (int o = 1; o < 16; o <<= 1) {
                        ps += __shfl_xor(ps, o, 64); pd += __shfl_xor(pd, o, 64);
                    }
                    if (mrow == 0) {
                        sals[mt * 16 + q * 4 + r][wv] = ps;
                        sald[mt * 16 + q * 4 + r][wv] = pd;
                    }
                }
            }
        }
    }
    __syncthreads();                     // A-tile dead; sals complete
    if (H == 1 && t < 64) {
        const int row = m0 + t;
        if (row < N_NODES) {
            als[row] = (sals[t][0] + sals[t][1] + sals[t][2] + sals[t][3]) * LOG2E;
            ald[row] = (sald[t][0] + sald[t][1] + sald[t][2] + sald[t][3]) * LOG2E;
        }
    }
    float* S = (float*)smem + wv * 16 * 68;   // 16 rows x 68 floats, wave-private (in As region)
    const int prow = lane >> 2, pj = lane & 3;   // pack: lane -> (row-in-tile, uint4 j)
#pragma unroll
    for (int mt = 0; mt < 4; mt++) {
#pragma unroll
        for (int i = 0; i < 4; i++)
#pragma unroll
            for (int r = 0; r < 4; r++)
                S[(q * 4 + r) * 68 + i * 16 + mrow] = acc[mt][i][r];
        // wave-internal LDS ordering: no barrier needed
        const float* cp = S + prow * 68 + pj * 16;
        uint4 o;
        o.x = pk4fp8(cp[0],  cp[1],  cp[2],  cp[3]);
        o.y = pk4fp8(cp[4],  cp[5],  cp[6],  cp[7]);
        o.z = pk4fp8(cp[8],  cp[9],  cp[10], cp[11]);
        o.w = pk4fp8(cp[12], cp[13], cp[14], cp[15]);
        const int row = m0 + mt * 16 + prow;
        if (row < N_NODES)
            ((uint4*)(Y8 + (size_t)row * 64))[wv * 4 + pj] = o;
    }
}

// layer-1 gather: R9 structure + SGPR-scalarized addressing. Indices are wave-uniform
// (all lanes read the same 16B of srclist), so readfirstlane + scalar index math moves
// the per-edge address chains onto the SALU pipe; loads become s[base]+v_laneoff.
__global__ __launch_bounds__(256) void gat_gather1(
        const int* __restrict__ row_start, const ushort* __restrict__ srclist,
        const float* __restrict__ als, const float* __restrict__ ald,
        const uint* __restrict__ xw8,                    // fp8 rows, 64 uints/row
        const float* __restrict__ bias,
        ushort* __restrict__ emb1b) {                    // [N][256] bf16
    const int wid = __builtin_amdgcn_readfirstlane(blockIdx.x * 4 + (threadIdx.x >> 6));
    const uint lane = threadIdx.x & 63;
    const uint h = lane >> 3;
    const float ald_n = ald[wid * HEADS_1 + h];
    const int beg = row_start[wid], end = row_start[wid + 1];

    float ex0 = __builtin_amdgcn_exp2f(leaky(als[wid * HEADS_1 + h] + ald_n));
    uint u = xw8[((uint)wid << 6) + lane];
    vf2 lo = __builtin_amdgcn_cvt_pk_f32_fp8((int)u, false);
    vf2 hi = __builtin_amdgcn_cvt_pk_f32_fp8((int)u, true);
    float den = ex0;
    vf2 exv0 = {ex0, ex0};
    vf2 a01 = exv0 * lo, a23 = exv0 * hi;

    for (int i = beg; i < end; i += 8) {
        uint4 svv = *(const uint4*)(srclist + i);   // same 16B in every lane
        uint d0 = __builtin_amdgcn_readfirstlane(svv.x);
        uint d1 = __builtin_amdgcn_readfirstlane(svv.y);
        uint d2 = __builtin_amdgcn_readfirstlane(svv.z);
        uint d3 = __builtin_amdgcn_readfirstlane(svv.w);
        uint ss[8];
        ss[0] = d0 & 0xffffu; ss[1] = d0 >> 16;
        ss[2] = d1 & 0xffffu; ss[3] = d1 >> 16;
        ss[4] = d2 & 0xffffu; ss[5] = d2 >> 16;
        ss[6] = d3 & 0xffffu; ss[7] = d3 >> 16;
        uint rr[8]; float ee[8];
#pragma unroll
        for (int j = 0; j < 8; j++) rr[j] = (xw8 + (ss[j] << 6))[lane];     // uniform base + lane
#pragma unroll
        for (int j = 0; j < 8; j++) ee[j] = (als + ss[j] * HEADS_1)[h];     // uniform base + h
#pragma unroll
        for (int j = 0; j < 8; j++) {
            float ex = __builtin_amdgcn_exp2f(leaky(ee[j] + ald_n));   // sentinel -> 0
            vf2 l2 = __builtin_amdgcn_cvt_pk_f32_fp8((int)rr[j], false);
            vf2 h2 = __builtin_amdgcn_cvt_pk_f32_fp8((int)rr[j], true);
            den += ex;
            vf2 exv = {ex, ex};
            a01 += exv * l2;
            a23 += exv * h2;
        }
    }
    float inv = 1.f / den;
    float4 bv = ((const float4*)bias)[lane];
    float4 r;
    r.x = a01[0] * inv + bv.x; r.y = a01[1] * inv + bv.y;
    r.z = a23[0] * inv + bv.z; r.w = a23[1] * inv + bv.w;
    r.x = r.x > 0.f ? r.x : __expf(r.x) - 1.f;
    r.y = r.y > 0.f ? r.y : __expf(r.y) - 1.f;
    r.z = r.z > 0.f ? r.z : __expf(r.z) - 1.f;
    r.w = r.w > 0.f ? r.w : __expf(r.w) - 1.f;
    uint2 p;
    p.x = (uint)f2bf(r.x) | ((uint)f2bf(r.y) << 16);
    p.y = (uint)f2bf(r.z) | ((uint)f2bf(r.w) << 16);
    ((uint2*)emb1b)[((uint)wid << 6) + lane] = p;
}

// layer-2 gather (R9 structure + scalarized addressing) fused with normalize + fp8 pack (PERMUTED).
__global__ __launch_bounds__(256) void gat_gather2(
        const int* __restrict__ row_start, const ushort* __restrict__ srclist,
        const float* __restrict__ als, const float* __restrict__ ald,
        const uint* __restrict__ xw8,                    // fp8 rows, 64 uints/row
        const float* __restrict__ bias,
        const ushort* __restrict__ emb1b,                // [N][256] bf16
        uint* __restrict__ embn8) {                      // [N][512] fp8 PERMUTED, 128 uints/row
    const int wid = __builtin_amdgcn_readfirstlane(blockIdx.x * 4 + (threadIdx.x >> 6));
    const uint lane = threadIdx.x & 63;
    const float ald_n = ald[wid];
    const int beg = row_start[wid], end = row_start[wid + 1];

    float ex0 = __builtin_amdgcn_exp2f(leaky(als[wid] + ald_n));
    uint u = xw8[((uint)wid << 6) + lane];
    vf2 lo = __builtin_amdgcn_cvt_pk_f32_fp8((int)u, false);
    vf2 hi = __builtin_amdgcn_cvt_pk_f32_fp8((int)u, true);
    float den = ex0;
    vf2 exv0 = {ex0, ex0};
    vf2 a01 = exv0 * lo, a23 = exv0 * hi;

    for (int i = beg; i < end; i += 8) {
        uint4 svv = *(const uint4*)(srclist + i);
        uint d0 = __builtin_amdgcn_readfirstlane(svv.x);
        uint d1 = __builtin_amdgcn_readfirstlane(svv.y);
        uint d2 = __builtin_amdgcn_readfirstlane(svv.z);
        uint d3 = __builtin_amdgcn_readfirstlane(svv.w);
        uint ss[8];
        ss[0] = d0 & 0xffffu; ss[1] = d0 >> 16;
        ss[2] = d1 & 0xffffu; ss[3] = d1 >> 16;
        ss[4] = d2 & 0xffffu; ss[5] = d2 >> 16;
        ss[6] = d3 & 0xffffu; ss[7] = d3 >> 16;
        uint rr[8]; float ee[8];
#pragma unroll
        for (int j = 0; j < 8; j++) rr[j] = (xw8 + (ss[j] << 6))[lane];   // uniform base + lane
#pragma unroll
        for (int j = 0; j < 8; j++) ee[j] = als[ss[j]];                   // fully uniform (s_load)
#pragma unroll
        for (int j = 0; j < 8; j++) {
            float ex = __builtin_amdgcn_exp2f(leaky(ee[j] + ald_n));   // sentinel -> 0
            vf2 l2 = __builtin_amdgcn_cvt_pk_f32_fp8((int)rr[j], false);
            vf2 h2 = __builtin_amdgcn_cvt_pk_f32_fp8((int)rr[j], true);
            den += ex;
            vf2 exv = {ex, ex};
            a01 += exv * l2;
            a23 += exv * h2;
        }
    }
    float inv = 1.f / den;
    float4 bv = ((const float4*)bias)[lane];
    float4 e2;
    e2.x = a01[0] * inv + bv.x; e2.y = a01[1] * inv + bv.y;
    e2.z = a23[0] * inv + bv.z; e2.w = a23[1] * inv + bv.w;
    uint2 u1 = ((const uint2*)emb1b)[((uint)wid << 6) + lane];
    float4 e1;
    e1.x = bfl(u1.x); e1.y = bfh(u1.x); e1.z = bfl(u1.y); e1.w = bfh(u1.y);

    float ssum = e1.x * e1.x + e1.y * e1.y + e1.z * e1.z + e1.w * e1.w
               + e2.x * e2.x + e2.y * e2.y + e2.z * e2.z + e2.w * e2.w;
#pragma unroll
    for (int o = 32; o > 0; o >>= 1) ssum += __shfl_xor(ssum, o, 64);
    float innv = 1.f / fmaxf(sqrtf(ssum), 1e-8f);

    uint p1 = pk4fp8(e1.x * innv, e1.y * innv, e1.z * innv, e1.w * innv);
    uint p2 = pk4fp8(e2.x * innv, e2.y * innv, e2.z * innv, e2.w * innv);
    // permuted store: within each 64B chunk j, out[q*16 + half*8 + b] = in[half*32 + q*8 + b]
    // so a dwordx4 at (q*16 + j*64) yields the two 8B MFMA k-fragments (k=2j, 2j+1) for lane q.
    const uint n1 = ((lane >> 4) << 4) | (((lane >> 1) & 3) << 2) | (((lane >> 3) & 1) << 1) | (lane & 1);
    embn8[((uint)wid << 7) + n1] = p1;        // emb1 part -> chunks j=0..3
    embn8[((uint)wid << 7) + 64 + n1] = p2;   // emb2 part -> chunks j=4..7
}

// ---------------- MFMA contrastive loss (fp8, permuted rows) ----------------

#define ROWU 140                        // 560 B row stride: 16B-aligned, b128 conflict-free

__global__ __launch_bounds__(1024, 8) void loss_mfma_kernel(
        const uint* __restrict__ embn8,    // [N][512] fp8 permuted, 128 uints/row
        const int* __restrict__ walks, const int* __restrict__ negs,
        float* __restrict__ out) {
    __shared__ __align__(16) uint srows8[WALK_LEN * ROWU];   // 35.8 KB
    __shared__ int wids[WALK_LEN];
    __shared__ float possum[WALK_LEN];
    __shared__ float negsum[WALK_LEN];
    const int b = blockIdx.x;                // walk
    const int t = threadIdx.x;
    const int w = __builtin_amdgcn_readfirstlane(t >> 6);   // 0..15
    const int lane = t & 63;
    const int mrow = lane & 15, q = lane >> 4;
    const char* embc = (const char*)embn8;   // byte rows, stride 512

    if (t < 64) wids[t] = walks[b * WALK_LEN + t];
    else if (t < 128) possum[t - 64] = 0.f;
    else if (t < 192) negsum[t - 128] = 0.f;

    // prefetch job0 (= w, always a neg tile) B rows into registers BEFORE the barriers:
    // latency rides under the staging drain.
    uint4 Bv[8];
    int pnode = negs[b * (WALK_LEN * NEG_S) + (w * 16 + mrow)];
    {
        const char* bp = embc + (((uint)pnode) << 9) + (uint)(q * 16);
#pragma unroll
        for (int j = 0; j < 8; j++) Bv[j] = *(const uint4*)(bp + j * 64);
    }
    __syncthreads();                         // wids ready

    // stage 64 walk rows (4 per wave, 2 rows per uint4 wave-instr)
    {
        const int rA = w * 4 + (lane >> 5);
        const int rB = rA + 2;
        const uint off = lane & 31;
        ((uint4*)(srows8 + rA * ROWU))[off] = ((const uint4*)embn8)[((uint)wids[rA] << 5) + off];
        ((uint4*)(srows8 + rB * ROWU))[off] = ((const uint4*)embn8)[((uint)wids[rB] << 5) + off];
    }
    __syncthreads();

#pragma unroll
    for (int ji = 0; ji < 3; ji++) {
        const int job = w + ji * 16;
        f32x4 acc0 = {0.f, 0.f, 0.f, 0.f};
        f32x4 acc1 = {0.f, 0.f, 0.f, 0.f};
        if (ji < 2 || w < 8) {
            // ---- neg tile: cands c = 16*job .. +15 (col = mrow), anchors = group job/10 ----
            const int albase = (job / 10) * 16;
            const int curnode = pnode;
            const int owner = (job * 16 + mrow) / 10;    // absolute anchor owning cand
            const char* ap = (const char*)(srows8 + (albase + mrow) * ROWU) + q * 16;
            __builtin_amdgcn_s_setprio(1);
#pragma unroll
            for (int j = 0; j < 4; j++) {
                i64x2 a = *(const i64x2*)(ap + j * 64);
                const i64x2 bb = *(const i64x2*)&Bv[j];
                acc0 = __builtin_amdgcn_mfma_f32_16x16x32_fp8_fp8(a[0], bb[0], acc0, 0, 0, 0);
                acc0 = __builtin_amdgcn_mfma_f32_16x16x32_fp8_fp8(a[1], bb[1], acc0, 0, 0, 0);
            }
#pragma unroll
            for (int j = 4; j < 8; j++) {
                i64x2 a = *(const i64x2*)(ap + j * 64);
                const i64x2 bb = *(const i64x2*)&Bv[j];
                acc1 = __builtin_amdgcn_mfma_f32_16x16x32_fp8_fp8(a[0], bb[0], acc1, 0, 0, 0);
                acc1 = __builtin_amdgcn_mfma_f32_16x16x32_fp8_fp8(a[1], bb[1], acc1, 0, 0, 0);
            }
            __builtin_amdgcn_s_setprio(0);
            // prefetch next job's B (Bv consumed above); latency hides under epilogue
            if (ji == 0 || (ji == 1 && w < 8)) {
                const int njob = job + 16;
                pnode = negs[b * (WALK_LEN * NEG_S) + (njob * 16 + mrow)];
                const char* bp = embc + (((uint)pnode) << 9) + (uint)(q * 16);
#pragma unroll
                for (int j = 0; j < 8; j++) Bv[j] = *(const uint4*)(bp + j * 64);
            }
#pragma unroll
            for (int reg = 0; reg < 4; reg++) {
                const int l_a = albase + q * 4 + reg;   // absolute anchor of this acc slot
                float e = 0.f;
                if (owner == l_a) {
                    bool msk = false;
#pragma unroll
                    for (int dj = -WINDOW; dj <= WINDOW; dj++) {
                        if (dj == 0) continue;
                        int p = l_a + dj;
                        if (p >= 0 && p < WALK_LEN && wids[p] == curnode) msk = true;
                    }
                    if (!msk) e = __expf((acc0[reg] + acc1[reg]) * INV_TEMP);
                }
                e = red16(e);
                if (mrow == 0 && e != 0.f) atomicAdd(&negsum[l_a], e);
            }
        } else {
            // ---- pos tile: group g = (w-8)>>1, row half = (w-8)&1 ----
            const int pj = w - 8;
            const int g = pj >> 1, half = pj & 1;
            const int albase = g * 16;
            const int base = (albase - WINDOW) > 0 ? (albase - WINDOW) : 0;
            const int hi = (albase + 15 + WINDOW) < (WALK_LEN - 1) ? (albase + 15 + WINDOW) : (WALK_LEN - 1);
            const int cnt = hi - base + 1;           // 21..26
            const int r = half * 16 + mrow;
            const int row = base + r;                // absolute walk pos of this B row
            const int rc = row < hi ? row : hi;      // clamp (masked by `use`)
            const char* ap = (const char*)(srows8 + (albase + mrow) * ROWU) + q * 16;
            const char* bp = (const char*)(srows8 + rc * ROWU) + q * 16;
            __builtin_amdgcn_s_setprio(1);
#pragma unroll
            for (int j = 0; j < 4; j++) {
                i64x2 a = *(const i64x2*)(ap + j * 64);
                i64x2 bb = *(const i64x2*)(bp + j * 64);
                acc0 = __builtin_amdgcn_mfma_f32_16x16x32_fp8_fp8(a[0], bb[0], acc0, 0, 0, 0);
                acc0 = __builtin_amdgcn_mfma_f32_16x16x32_fp8_fp8(a[1], bb[1], acc0, 0, 0, 0);
            }
#pragma unroll
            for (int j = 4; j < 8; j++) {
                i64x2 a = *(const i64x2*)(ap + j * 64);
                i64x2 bb = *(const i64x2*)(bp + j * 64);
                acc1 = __builtin_amdgcn_mfma_f32_16x16x32_fp8_fp8(a[0], bb[0], acc1, 0, 0, 0);
                acc1 = __builtin_amdgcn_mfma_f32_16x16x32_fp8_fp8(a[1], bb[1], acc1, 0, 0, 0);
            }
            __builtin_amdgcn_s_setprio(0);
#pragma unroll
            for (int reg = 0; reg < 4; reg++) {
                const int l_a = albase + q * 4 + reg;
                const int d = row - l_a;
                bool use = (r < cnt) && (d != 0) && (d >= -WINDOW) && (d <= WINDOW);
                float e = use ? __expf((acc0[reg] + acc1[reg]) * INV_TEMP) : 0.f;
                e = red16(e);
                if (mrow == 0 && e != 0.f) atomicAdd(&possum[l_a], e);
            }
        }
    }
    __syncthreads();
    if (t < 64) {
        float term = logf(1.f + negsum[t] / possum[t]);   // possum > 0 always
#pragma unroll
        for (int o = 32; o > 0; o >>= 1) term += __shfl_xor(term, o, 64);
        if (t == 0) atomicAdd(out, term);
    }
}

extern "C" void kernel_launch(void* const* d_in, const int* in_sizes, int n_in,
                              void* d_out, int out_size, void* d_ws, size_t ws_size,
                              hipStream_t stream) {
    const float* x      = (const float*)d_in[0];
    const int*   ei     = (const int*)d_in[1];
    const int*   walks  = (const int*)d_in[2];
    const int*   negs   = (const int*)d_in[3];
    const float* W1     = (const float*)d_in[4];
    const float* a_src1 = (const float*)d_in[5];
    const float* a_dst1 = (const float*)d_in[6];
    const float* b1     = (const float*)d_in[7];
    const float* W2     = (const float*)d_in[8];
    const float* a_src2 = (const float*)d_in[9];
    const float* a_dst2 = (const float*)d_in[10];
    const float* b2     = (const float*)d_in[11];
    float* out = (float*)d_out;

    float* ws = (float*)d_ws;
    size_t off = 0;
    // every region aligned to 1024 B (256 floats) so row starts stay cache-line aligned
#define ALIGN_OFF off = (off + 255) & ~(size_t)255
    float* r_xw8   = ws + off; off += (size_t)(N_NODES + 1) * 64;  ALIGN_OFF;  // [N+1][256] fp8 (sentinel row)
    float* r_emb1b = ws + off; off += (size_t)N_PAD * 128;         ALIGN_OFF;  // [Npad][256] bf16
    float* r_embn8 = ws + off; off += (size_t)N_NODES * 128;       ALIGN_OFF;  // [N][512] fp8 permuted
    float* r_xb    = ws + off; off += (size_t)N_PAD * 64;          ALIGN_OFF;  // [Npad][128] bf16
    float* r_wt1   = ws + off; off += 256 * 64;                    ALIGN_OFF;  // [256][128] bf16
    float* r_wt2   = ws + off; off += 256 * 128;                   ALIGN_OFF;  // [256][256] bf16
    float* als1  = ws + off; off += (N_NODES + 1) * HEADS_1;       ALIGN_OFF;  // sentinel row
    float* ald1  = ws + off; off += N_NODES * HEADS_1;             ALIGN_OFF;
    float* als2  = ws + off; off += N_NODES + 1;                   ALIGN_OFF;  // sentinel
    float* ald2  = ws + off; off += N_NODES;                       ALIGN_OFF;
    int* excl      = (int*)(ws + off); off += N_NODES;             ALIGN_OFF;
    int* bsum      = (int*)(ws + off); off += 256;                 ALIGN_OFF;
    int* row_start = (int*)(ws + off); off += N_NODES + 1;         ALIGN_OFF;
    uint* gbucket  = (uint*)(ws + off); off += (size_t)NGRP * NB * GCAP; ALIGN_OFF;  // 4.8 MB group-private regions
    int* gcur      = (int*)(ws + off); off += 1024;                ALIGN_OFF;
    ushort* srclist = (ushort*)(ws + off); off += E_PAD / 2;       ALIGN_OFF;  // 2B entries
    uint*   xw8   = (uint*)r_xw8;
    ushort* emb1b = (ushort*)r_emb1b;
    uint*   embn8 = (uint*)r_embn8;
    ushort* xb    = (ushort*)r_xb;
    ushort* wt1   = (ushort*)r_wt1;
    ushort* wt2   = (ushort*)r_wt2;

    hipMemsetAsync(out, 0, sizeof(float) * out_size, stream);
    hipMemsetAsync(gcur, 0, sizeof(int) * NGRP * NB, stream);

    // ---- fused prep (bf16 convert + W transposes + sentinel init + append-only binning) ----
    prep_kernel<<<PREP_GRID, 256, 0, stream>>>(
        x, ei, W1, W2, (uint*)xb, wt1, wt2, gbucket, gcur, als1, als2, xw8);

    // ---- CSR scans: degree-from-buckets (LDS counters) + per-bucket prefix + global prefix ----
    scan_a<<<NB, 256, 0, stream>>>(gbucket, gcur, excl, bsum);
    scan_b<<<1, 128, 0, stream>>>(bsum, row_start);
    scan_c2<<<SCAN_BLOCKS, 256, 0, stream>>>(excl, bsum, row_start);

    // ---- layer 1 gemm FUSED with LDS-window scatter (98 scatter + 782 gemm blocks) ----
    mfma_gemm64<128, HEADS_1><<<NB + N_PAD / 64, 256, 0, stream>>>(
        xb, wt1, xw8, a_src1, a_dst1, als1, ald1, gbucket, gcur, row_start, srclist);
    gat_gather1<<<N_NODES / 4, 256, 0, stream>>>(
        row_start, srclist, als1, ald1, xw8, b1, emb1b);

    // ---- layer 2 (heads=1, hid=256), fused als/ald + normalize + fp8 pack (permuted) ----
    mfma_gemm64<256, 1><<<N_PAD / 64, 256, 0, stream>>>(
        emb1b, wt2, xw8, a_src2, a_dst2, als2, ald2, gbucket, gcur, row_start, srclist);
    gat_gather2<<<N_NODES / 4, 256, 0, stream>>>(
        row_start, srclist, als2, ald2, xw8, b2, emb1b, embn8);

    // ---- contrastive loss (fp8 MFMA, 1 block/walk, reg-prefetch pipeline) ----
    loss_mfma_kernel<<<NUM_WALKS, 1024, 0, stream>>>(embn8, walks, negs, out);
}